// Round 10
// baseline (355.905 us; speedup 1.0000x reference)
//
#include <hip/hip_runtime.h>
#include <hip/hip_bf16.h>
#include <stdint.h>

// B=2, T=2048, D=1024, H=16, HD=64, SCALE=1/8. Softmax is over the HEAD axis.
typedef __bf16 bf16;
typedef __attribute__((ext_vector_type(8))) __bf16 bf16x8;
typedef __attribute__((ext_vector_type(4))) __bf16 bf16x4;
typedef __attribute__((ext_vector_type(2))) __bf16 bf16x2;
typedef __attribute__((ext_vector_type(4))) float f32x4;
typedef __attribute__((ext_vector_type(16))) float f32x16;
typedef __attribute__((ext_vector_type(4))) unsigned uint4v;

#define MFMA_16x16x32(a, b, c) __builtin_amdgcn_mfma_f32_16x16x32_bf16((a), (b), (c), 0, 0, 0)
#define MFMA_32x32x16(a, b, c) __builtin_amdgcn_mfma_f32_32x32x16_bf16((a), (b), (c), 0, 0, 0)

__device__ __forceinline__ void gld_lds16(const void* g, void* l) {
    __builtin_amdgcn_global_load_lds(
        (const __attribute__((address_space(1))) void*)g,
        (__attribute__((address_space(3))) void*)l,
        16, 0, 0);
}

__device__ __forceinline__ unsigned pk2(float a, float b) {
    bf16x2 t; t[0] = (bf16)a; t[1] = (bf16)b;
    return __builtin_bit_cast(unsigned, t);
}

// ---------- fp32 -> bf16 convert (vectorized) ----------
__global__ void cvt_f32_bf16(const float* __restrict__ in, bf16* __restrict__ out, int n) {
    int i = (blockIdx.x * blockDim.x + threadIdx.x) * 8;
    if (i >= n) return;
    f32x4 a = *(const f32x4*)(in + i);
    f32x4 b = *(const f32x4*)(in + i + 4);
    bf16x8 o;
#pragma unroll
    for (int j = 0; j < 4; ++j) { o[j] = (bf16)a[j]; o[j + 4] = (bf16)b[j]; }
    *(bf16x8*)(out + i) = o;
}

// ---------- transpose + convert: in[R][C] f32 -> out[C][R] bf16 ----------
__global__ void transpose_cvt(const float* __restrict__ in, bf16* __restrict__ out, int R, int C) {
    __shared__ float tile[32][33];
    int c0 = blockIdx.x * 32, r0 = blockIdx.y * 32;
    int tc = threadIdx.x & 31, tr = threadIdx.x >> 5; // tr in 0..7
#pragma unroll
    for (int i = 0; i < 4; ++i) {
        int r = tr + i * 8;
        tile[r][tc] = in[(size_t)(r0 + r) * C + c0 + tc];
    }
    __syncthreads();
#pragma unroll
    for (int i = 0; i < 4; ++i) {
        int r = tr + i * 8; // out row = original column
        out[(size_t)(c0 + r) * R + r0 + tc] = (bf16)tile[tc][r];
    }
}

// ---------- bf16 GEMM, C = A[M,K] @ Bt[N,K]^T ; 128x128 tile, BK=32, 4 waves ----------
// EPI==0: scatter qkv -> q (PRE-SCALED by 0.125*log2e), k, v^T. EPI==1: fp32+bias.
template <int EPI>
__global__ void __launch_bounds__(256) gemm_bf16(
    const bf16* __restrict__ A, const bf16* __restrict__ Bt, int M, int N, int K,
    float* __restrict__ Cf, const float* __restrict__ bias,
    bf16* __restrict__ q_out, bf16* __restrict__ k_out, bf16* __restrict__ v_out)
{
    __shared__ bf16 As[128 * 32];
    __shared__ bf16 Bs[128 * 32];
    const int t = threadIdx.x, w = t >> 6, l = t & 63;
    const int l15 = l & 15, lh = l >> 4;
    const int m0 = blockIdx.y * 128, n0 = blockIdx.x * 128;
    const int wm = w >> 1, wn = w & 1;

    const int srow = w * 16 + (l >> 2);
    const int scol = (l & 3) * 8;
    const bf16* gA = A + (size_t)(m0 + srow) * K + scol;
    const bf16* gB = Bt + (size_t)(n0 + srow) * K + scol;
    char* lA = (char*)As + w * 1024;
    char* lB = (char*)Bs + w * 1024;

    f32x4 acc[4][4] = {};

    for (int kt = 0; kt < K; kt += 32) {
        __syncthreads();
        gld_lds16(gA + kt, lA);
        gld_lds16(gA + (size_t)64 * K + kt, lA + 4096);
        gld_lds16(gB + kt, lB);
        gld_lds16(gB + (size_t)64 * K + kt, lB + 4096);
        asm volatile("s_waitcnt vmcnt(0)" ::: "memory");
        __syncthreads();

        const bf16* pa = As + (wm * 64 + l15) * 32 + lh * 8;
        const bf16* pb = Bs + (wn * 64 + l15) * 32 + lh * 8;
        bf16x8 af[4], bfr[4];
#pragma unroll
        for (int i = 0; i < 4; ++i) {
            af[i]  = *(const bf16x8*)(pa + i * 512);
            bfr[i] = *(const bf16x8*)(pb + i * 512);
        }
#pragma unroll
        for (int mi = 0; mi < 4; ++mi)
#pragma unroll
            for (int ni = 0; ni < 4; ++ni)
                acc[mi][ni] = MFMA_16x16x32(af[mi], bfr[ni], acc[mi][ni]);
    }

    if (EPI == 1) {
#pragma unroll
        for (int ni = 0; ni < 4; ++ni) {
            int n = n0 + wn * 64 + ni * 16 + l15;
            float bb = bias[n];
#pragma unroll
            for (int mi = 0; mi < 4; ++mi)
#pragma unroll
                for (int r = 0; r < 4; ++r) {
                    int m = m0 + wm * 64 + mi * 16 + lh * 4 + r;
                    Cf[(size_t)m * N + n] = acc[mi][ni][r] + bb;
                }
        }
    } else {
        const int which = n0 >> 10; // 0:q 1:k 2:v — uniform per block
        const float QSCL = 0.125f * 1.44269504089f; // fold softmax scale*log2e into Q
#pragma unroll
        for (int ni = 0; ni < 4; ++ni) {
            int n = n0 + wn * 64 + ni * 16 + l15;
            int h = (n >> 6) & 15;
            int d = n & 63;
#pragma unroll
            for (int mi = 0; mi < 4; ++mi)
#pragma unroll
                for (int r = 0; r < 4; ++r) {
                    int m = m0 + wm * 64 + mi * 16 + lh * 4 + r;
                    int b = m >> 11, tt = m & 2047;
                    float av = acc[mi][ni][r];
                    size_t hb = (size_t)b * 16 + h;
                    if (which == 0)      q_out[(hb * 2048 + tt) * 64 + d] = (bf16)(av * QSCL);
                    else if (which == 1) k_out[(hb * 2048 + tt) * 64 + d] = (bf16)av;
                    else                 v_out[(hb * 64 + d) * 2048 + tt] = (bf16)av;
                }
        }
    }
}

// ---------- kernel A: head-sum denominators, barrier-free ----------
// wave = (b, qtile32, kslice64). For all 16 heads: s = Q.K^T (32x32 tile via
// 4 chained mfma_32x32x16), acc += exp2(s) in f32x16 registers. Writes
// inv[b][q][k] = rcp(acc) as bf16, coalesced (lane = k). No LDS, no barriers.
__global__ void __launch_bounds__(256, 3) colsum_kernel(
    const bf16* __restrict__ Q, const bf16* __restrict__ Kmat, bf16* __restrict__ inv)
{
    const int t = threadIdx.x, w = t >> 6, l = t & 63;
    const int l31 = l & 31, l5 = l >> 5;
    const int bid = blockIdx.x;
    const int ksl = ((bid & 7) << 2) | w;      // XCD-pinned k-slice (32 slices)
    const int rest = bid >> 3;
    const int qt = rest & 63;
    const int b = rest >> 6;
    const int q0 = qt * 32;
    const int k0b = ksl * 64;

    f32x16 acc[2] = {};
    for (int h = 0; h < 16; ++h) {
        const size_t hq = ((size_t)b * 16 + h) * (2048 * 64);
        // Q A-frags: m = q = q0+l31, contraction d = dc*16 + 8*l5 + j
        bf16x8 qf[4];
        const bf16* qp = Q + hq + (size_t)(q0 + l31) * 64 + l5 * 8;
#pragma unroll
        for (int dc = 0; dc < 4; ++dc) qf[dc] = *(const bf16x8*)(qp + dc * 16);
#pragma unroll
        for (int g2 = 0; g2 < 2; ++g2) {
            const int k0 = k0b + g2 * 32;
            // K B-frags: n = k = k0+l31
            bf16x8 kf[4];
            const bf16* kp = Kmat + hq + (size_t)(k0 + l31) * 64 + l5 * 8;
#pragma unroll
            for (int dc = 0; dc < 4; ++dc) kf[dc] = *(const bf16x8*)(kp + dc * 16);
            f32x16 s = {};
#pragma unroll
            for (int dc = 0; dc < 4; ++dc) s = MFMA_32x32x16(qf[dc], kf[dc], s);
#pragma unroll
            for (int r = 0; r < 16; ++r)
                acc[g2][r] += __builtin_amdgcn_exp2f(s[r]);
        }
    }
    // write inv: D rows q = q0 + (r&3)+8*(r>>2)+4*l5, col k = k0+l31 (coalesced)
#pragma unroll
    for (int g2 = 0; g2 < 2; ++g2) {
        const int k0 = k0b + g2 * 32;
#pragma unroll
        for (int r = 0; r < 16; ++r) {
            int q = q0 + (r & 3) + 8 * (r >> 2) + 4 * l5;
            inv[((size_t)b * 2048 + q) * 2048 + k0 + l31] =
                (bf16)__builtin_amdgcn_rcpf(acc[g2][r]);
        }
    }
}

// ---------- kernel B: per-head attention, barrier-free ----------
// wave = (b, h, qtile32, khalf). Recomputes scores (bit-identical MFMA),
// P = exp2(s) * inv (inv preloaded from kernel A), PV accumulates o in regs.
// P redistribution D-layout -> A-frag via cvt_pk + v_permlane32_swap_b32 (T12).
// No LDS, no barriers; h-pairs XCD-pinned for K/V L2 residency.
__global__ void __launch_bounds__(256, 3) pv_kernel(
    const bf16* __restrict__ Q, const bf16* __restrict__ Kmat, const bf16* __restrict__ Vt,
    const bf16* __restrict__ inv, bf16* __restrict__ p0, bf16* __restrict__ p1)
{
    const int t = threadIdx.x, w = t >> 6, l = t & 63;
    const int l31 = l & 31, l5 = l >> 5;
    const int bid = blockIdx.x;
    const int hp = bid & 7;                    // XCD-pinned head pair
    const int rr = bid >> 3;
    const int h = hp * 2 + (rr & 1);
    const int b = (rr >> 1) & 1;
    const int ks = (rr >> 2) & 1;
    const int qt = ((rr >> 3) << 2) | w;       // 0..63
    const int q0 = qt * 32;

    const size_t hq = ((size_t)b * 16 + h) * (2048 * 64); // [B,H,T,64]
    const size_t hv = ((size_t)b * 16 + h) * (64 * 2048); // [B,H,64,2048]

    // Q B-frags (resident): n = q = q0+l31, d = dc*16 + 8*l5 + j
    bf16x8 qf[4];
    {
        const bf16* qp = Q + hq + (size_t)(q0 + l31) * 64 + l5 * 8;
#pragma unroll
        for (int dc = 0; dc < 4; ++dc) qf[dc] = *(const bf16x8*)(qp + dc * 16);
    }
    const bf16* ivp = inv + ((size_t)b * 2048 + q0 + l31) * 2048 + l5 * 4;

    f32x16 o[2] = {}; // [d-tile]; rows q=crow(r), col d = dt*32+l31

    for (int g = 0; g < 32; ++g) {
        const int k0 = ks * 1024 + g * 32;
        // K A-frags: m = k = k0+l31
        bf16x8 kf[4];
        const bf16* kp = Kmat + hq + (size_t)(k0 + l31) * 64 + l5 * 8;
#pragma unroll
        for (int dc = 0; dc < 4; ++dc) kf[dc] = *(const bf16x8*)(kp + dc * 16);
        // swapped score: D[k][q]; lane q=l31, k=(r&3)+8*(r>>2)+4*l5
        f32x16 s = {};
#pragma unroll
        for (int dc = 0; dc < 4; ++dc) s = MFMA_32x32x16(kf[dc], qf[dc], s);
        // inv loads: 4 x b64 (k-quads at 8g'+4*l5)
        bf16x4 iv[4];
#pragma unroll
        for (int gq = 0; gq < 4; ++gq) iv[gq] = *(const bf16x4*)(ivp + k0 + gq * 8);
        // P = exp2(s)*inv -> bf16 pairs -> permlane32_swap -> PV A-frags
        bf16x8 pa[2];
#pragma unroll
        for (int kh = 0; kh < 2; ++kh) {
            float p[8];
#pragma unroll
            for (int i = 0; i < 8; ++i)
                p[i] = __builtin_amdgcn_exp2f(s[kh * 8 + i]) * (float)iv[kh * 2 + (i >> 2)][i & 3];
            unsigned u0 = pk2(p[0], p[1]);
            unsigned u1 = pk2(p[2], p[3]);
            unsigned u2 = pk2(p[4], p[5]);
            unsigned u3 = pk2(p[6], p[7]);
            // swap a-upper <-> b-lower: yields A-frag dwords c'=0/2 and c'=1/3
            asm volatile("v_permlane32_swap_b32 %0, %1" : "+v"(u0), "+v"(u2));
            asm volatile("v_permlane32_swap_b32 %0, %1" : "+v"(u1), "+v"(u3));
            uint4v uu = {u0, u1, u2, u3};
            pa[kh] = __builtin_bit_cast(bf16x8, uu);
        }
        // PV: o[dt] += pa[kt] @ V  (V^T b128, k-contiguous)
#pragma unroll
        for (int kt = 0; kt < 2; ++kt)
#pragma unroll
            for (int dt = 0; dt < 2; ++dt) {
                bf16x8 vb = *(const bf16x8*)(Vt + hv + (size_t)(dt * 32 + l31) * 2048
                                             + k0 + kt * 16 + l5 * 8);
                o[dt] = MFMA_32x32x16(pa[kt], vb, o[dt]);
            }
    }
    // write partial: part[ks][b][t=q][h*64+d]
    bf16* dst = (ks == 0 ? p0 : p1) + (size_t)b * (2048 * 1024);
#pragma unroll
    for (int dt = 0; dt < 2; ++dt)
#pragma unroll
        for (int r = 0; r < 16; ++r) {
            int q = q0 + (r & 3) + 8 * (r >> 2) + 4 * l5;
            dst[(size_t)q * 1024 + h * 64 + dt * 32 + l31] = (bf16)o[dt][r];
        }
}

// ---------- sum the two k-half partials -> attn bf16 ----------
__global__ void reduce_part2(const bf16* __restrict__ p0, const bf16* __restrict__ p1,
                             bf16* __restrict__ out, int n) {
    int i = (blockIdx.x * blockDim.x + threadIdx.x) * 8;
    if (i >= n) return;
    bf16x8 a = *(const bf16x8*)(p0 + i);
    bf16x8 b = *(const bf16x8*)(p1 + i);
    bf16x8 o;
#pragma unroll
    for (int j = 0; j < 8; ++j) o[j] = (bf16)((float)a[j] + (float)b[j]);
    *(bf16x8*)(out + i) = o;
}

extern "C" void kernel_launch(void* const* d_in, const int* in_sizes, int n_in,
                              void* d_out, int out_size, void* d_ws, size_t ws_size,
                              hipStream_t stream)
{
    const float* x      = (const float*)d_in[0];
    const float* w_qkv  = (const float*)d_in[1];
    const float* w_proj = (const float*)d_in[2];
    const float* b_proj = (const float*)d_in[3];
    float* out = (float*)d_out;

    // workspace layout (58 MiB)
    char* ws = (char*)d_ws;
    const size_t MB = 1048576;
    bf16* wprojT = (bf16*)(ws + 0 * MB);   //  2 MiB  w_proj^T bf16 [1024,1024]
    bf16* xb     = (bf16*)(ws + 2 * MB);   //  8 MiB  x bf16 (later: part0/attnb)
    bf16* wqkvT  = (bf16*)(ws + 10 * MB);  //  6 MiB  w_qkv^T bf16 (later: part1)
    bf16* qb     = (bf16*)(ws + 18 * MB);  //  8 MiB  Q  [B,H,T,HD] (pre-scaled)
    bf16* kb     = (bf16*)(ws + 26 * MB);  //  8 MiB  K  [B,H,T,HD]
    bf16* vt     = (bf16*)(ws + 34 * MB);  //  8 MiB  V^T[B,H,HD,T]
    bf16* invb   = (bf16*)(ws + 42 * MB);  // 16 MiB  inv[b][q][k] bf16
    bf16* part0  = (bf16*)(ws + 2 * MB);   //  8 MiB  (over xb, dead after gemm1)
    bf16* part1  = (bf16*)(ws + 10 * MB);  //  8 MiB  (over wqkvT + gap)
    bf16* attnb  = (bf16*)(ws + 2 * MB);   //  8 MiB  = part0 (in-place reduce)

    cvt_f32_bf16<<<2048, 256, 0, stream>>>(x, xb, 4194304);
    transpose_cvt<<<dim3(96, 32), 256, 0, stream>>>(w_qkv, wqkvT, 1024, 3072);
    transpose_cvt<<<dim3(32, 32), 256, 0, stream>>>(w_proj, wprojT, 1024, 1024);

    // qkv projection: [4096,1024] @ [1024,3072] -> scatter to q/k/v^T
    gemm_bf16<0><<<dim3(24, 32), 256, 0, stream>>>(xb, wqkvT, 4096, 3072, 1024,
                                                   nullptr, nullptr, qb, kb, vt);
    // head-axis softmax denominators (barrier-free, all heads per wave)
    colsum_kernel<<<1024, 256, 0, stream>>>(qb, kb, invb);
    // per-head scores+PV (barrier-free, recompute + inv)
    pv_kernel<<<1024, 256, 0, stream>>>(qb, kb, vt, invb, part0, part1);
    reduce_part2<<<2048, 256, 0, stream>>>(part0, part1, attnb, 4194304);
    // output projection + bias -> fp32 d_out
    gemm_bf16<1><<<dim3(8, 32), 256, 0, stream>>>(attnb, wprojT, 4096, 1024, 1024,
                                                  out, b_proj, nullptr, nullptr, nullptr);

    (void)in_sizes; (void)n_in; (void)out_size; (void)ws_size;
}